// Round 2
// baseline (6960.690 us; speedup 1.0000x reference)
//
#include <hip/hip_runtime.h>
#include <math.h>

#define Lq 128
#define Bq 32
#define Hq 512
#define VOC 32000

// ---------------- embedding gather: x_tm[t][b][e] ----------------
__global__ __launch_bounds__(256) void embed_k(const int* __restrict__ word,
                                               const float* __restrict__ emb,
                                               float* __restrict__ x_tm) {
  int r = blockIdx.x * 2 + (threadIdx.x >> 7);   // row = t*32+b, 0..4095
  int e = threadIdx.x & 127;
  int t = r >> 5, b = r & 31;
  int w = word[b * Lq + t];
  x_tm[(size_t)r * 128 + e] = emb[(size_t)w * 128 + e];
}

// ---------------- generic fp32 GEMM: C[M][N] = A[M][K] @ W[N][K]^T + bias ----------------
// tiles 128x128, BK=32, thread tile 8x8
__global__ __launch_bounds__(256) void gemm_k(const float* __restrict__ A,
                                              const float* __restrict__ W,
                                              const float* __restrict__ bias,
                                              float* __restrict__ C,
                                              int N, int K, int relu) {
  __shared__ float As[32][132];
  __shared__ float Ws[32][132];
  int tid = threadIdx.x;
  int tx = tid & 15, ty = tid >> 4;
  int rb = blockIdx.y * 128, cb = blockIdx.x * 128;
  float acc[8][8];
#pragma unroll
  for (int i = 0; i < 8; ++i)
#pragma unroll
    for (int j = 0; j < 8; ++j) acc[i][j] = 0.f;

  for (int k0 = 0; k0 < K; k0 += 32) {
#pragma unroll
    for (int j = 0; j < 4; ++j) {
      int f = tid + 256 * j;            // 0..1023
      int r = f >> 3, kq = (f & 7) * 4;
      float4 va = *(const float4*)&A[(size_t)(rb + r) * K + k0 + kq];
      As[kq + 0][r] = va.x; As[kq + 1][r] = va.y; As[kq + 2][r] = va.z; As[kq + 3][r] = va.w;
      float4 vw = *(const float4*)&W[(size_t)(cb + r) * K + k0 + kq];
      Ws[kq + 0][r] = vw.x; Ws[kq + 1][r] = vw.y; Ws[kq + 2][r] = vw.z; Ws[kq + 3][r] = vw.w;
    }
    __syncthreads();
#pragma unroll 8
    for (int kk = 0; kk < 32; ++kk) {
      float a[8], w[8];
      *(float4*)&a[0] = *(const float4*)&As[kk][ty * 8];
      *(float4*)&a[4] = *(const float4*)&As[kk][ty * 8 + 4];
      *(float4*)&w[0] = *(const float4*)&Ws[kk][tx * 8];
      *(float4*)&w[4] = *(const float4*)&Ws[kk][tx * 8 + 4];
#pragma unroll
      for (int i = 0; i < 8; ++i)
#pragma unroll
        for (int j = 0; j < 8; ++j)
          acc[i][j] = fmaf(a[i], w[j], acc[i][j]);
    }
    __syncthreads();
  }
#pragma unroll
  for (int i = 0; i < 8; ++i) {
    int r = rb + ty * 8 + i;
#pragma unroll
    for (int j = 0; j < 8; j += 4) {
      int c = cb + tx * 8 + j;
      float4 o;
      o.x = acc[i][j + 0] + bias[c + 0];
      o.y = acc[i][j + 1] + bias[c + 1];
      o.z = acc[i][j + 2] + bias[c + 2];
      o.w = acc[i][j + 3] + bias[c + 3];
      if (relu) {
        o.x = fmaxf(o.x, 0.f); o.y = fmaxf(o.y, 0.f);
        o.z = fmaxf(o.z, 0.f); o.w = fmaxf(o.w, 0.f);
      }
      *(float4*)&C[(size_t)r * N + c] = o;
    }
  }
}

// ---------------- one LSTM time step (both directions), per-WG 4 h-cols ----------------
// grid 256: bid>>7 = dir, (bid&127)*4 = h-col base. H double-buffered by step parity.
__global__ __launch_bounds__(256) void lstm_step_k(
    const float* __restrict__ GX, const float* __restrict__ Whh,
    const float* __restrict__ mask, const float* __restrict__ Hprev,
    float* __restrict__ Hnext, float* __restrict__ Cst,
    float* __restrict__ seq_out, int s) {
  __shared__ float h_s[32][513];     // pitch 513: (4*513)%32==4 -> conflict-free-ish
  __shared__ float w_s[16][513];
  __shared__ float red[8][32][16];
  __shared__ float gate2[32][16];
  int tid = threadIdx.x;
  int d = blockIdx.x >> 7;
  int hcB = (blockIdx.x & 127) * 4;
  int t = d ? (Lq - 1 - s) : s;
  const float* Hd = Hprev + d * (Bq * Hq);
  float* Hn = Hnext + d * (Bq * Hq);
  float* Cd = Cst + d * (Bq * Hq);

  // stage h (32x512) into LDS
#pragma unroll
  for (int j = 0; j < 16; ++j) {
    int f = tid + 256 * j;
    int b = f >> 7, k4 = (f & 127) * 4;
    float4 v = *(const float4*)&Hd[b * 512 + k4];
    h_s[b][k4 + 0] = v.x; h_s[b][k4 + 1] = v.y; h_s[b][k4 + 2] = v.z; h_s[b][k4 + 3] = v.w;
  }
  // stage 16 Whh rows (c = ty*4+hcl -> g = d*2048 + ty*512 + hcB + hcl)
#pragma unroll
  for (int j = 0; j < 8; ++j) {
    int f = tid + 256 * j;
    int c = f >> 7, k4 = (f & 127) * 4;
    int grow = d * 2048 + (c >> 2) * 512 + hcB + (c & 3);
    float4 v = *(const float4*)&Whh[(size_t)grow * 512 + k4];
    w_s[c][k4 + 0] = v.x; w_s[c][k4 + 1] = v.y; w_s[c][k4 + 2] = v.z; w_s[c][k4 + 3] = v.w;
  }
  __syncthreads();

  // 4x4 register tiles, k-split 8
  int tile = tid & 31, ks = tid >> 5;
  int b0 = (tile & 7) * 4, c0 = (tile >> 3) * 4;
  float acc[4][4];
#pragma unroll
  for (int i = 0; i < 4; ++i)
#pragma unroll
    for (int j = 0; j < 4; ++j) acc[i][j] = 0.f;
  int kb = ks * 64;
#pragma unroll 4
  for (int k = kb; k < kb + 64; ++k) {
    float hv[4], wv[4];
    hv[0] = h_s[b0 + 0][k]; hv[1] = h_s[b0 + 1][k];
    hv[2] = h_s[b0 + 2][k]; hv[3] = h_s[b0 + 3][k];
    wv[0] = w_s[c0 + 0][k]; wv[1] = w_s[c0 + 1][k];
    wv[2] = w_s[c0 + 2][k]; wv[3] = w_s[c0 + 3][k];
#pragma unroll
    for (int i = 0; i < 4; ++i)
#pragma unroll
      for (int j = 0; j < 4; ++j)
        acc[i][j] = fmaf(hv[i], wv[j], acc[i][j]);
  }
#pragma unroll
  for (int i = 0; i < 4; ++i)
#pragma unroll
    for (int j = 0; j < 4; ++j) red[ks][b0 + i][c0 + j] = acc[i][j];
  __syncthreads();

  // k-split reduce + add GX
  for (int o = tid; o < 512; o += 256) {
    int b = o >> 4, c = o & 15;
    float g = 0.f;
#pragma unroll
    for (int q = 0; q < 8; ++q) g += red[q][b][c];
    g += GX[(size_t)(t * 32 + b) * 4096 + d * 2048 + (c >> 2) * 512 + hcB + (c & 3)];
    gate2[b][c] = g;
  }
  __syncthreads();

  // cell update for this WG's 4 h-cols (128 threads)
  if (tid < 128) {
    int b = tid >> 2, hcl = tid & 3;
    int hh = hcB + hcl;
    float iv = gate2[b][0 + hcl], fv = gate2[b][4 + hcl];
    float gv = gate2[b][8 + hcl], ov = gate2[b][12 + hcl];
    float cp = Cd[b * 512 + hh];
    float hp = h_s[b][hh];
    float m = mask[b * Lq + t];
    float ig = 1.f / (1.f + expf(-iv));
    float fg = 1.f / (1.f + expf(-fv));
    float gg = tanhf(gv);
    float og = 1.f / (1.f + expf(-ov));
    float cn = fg * cp + ig * gg;
    float hn = og * tanhf(cn);
    float ho = hp + (hn - hp) * m;
    float co = cp + (cn - cp) * m;
    Cd[b * 512 + hh] = co;
    Hn[b * 512 + hh] = ho;
    seq_out[(size_t)(t * 32 + b) * 1024 + d * 512 + hh] = ho;
  }
}

// ---------------- decoder: fused logits + per-row chunk reductions ----------------
// grid (63 vchunks of 512, 64 rowblocks of 64). part[chunk][row] = {max, sumexp, argmaxf, tgtlogit}
__global__ __launch_bounds__(256) void dec_k(
    const float* __restrict__ hid, const float* __restrict__ w2,
    const float* __restrict__ b2, const int* __restrict__ tgt_word,
    float* __restrict__ part) {
  __shared__ float ht[128][68];   // [k][row]
  __shared__ float wt[128][68];   // [k][v]
  __shared__ float lg[64][68];    // [row][v]
  int tid = threadIdx.x;
  int vb = blockIdx.x, rb = blockIdx.y;
  int r0 = rb * 64, v0 = vb * 512;
  // stage hid rows (64 x 128)
#pragma unroll
  for (int j = 0; j < 8; ++j) {
    int f = tid + 256 * j;              // 0..2047
    int r = f >> 5, kq = (f & 31) * 4;
    float4 v = *(const float4*)&hid[(size_t)(r0 + r) * 128 + kq];
    ht[kq + 0][r] = v.x; ht[kq + 1][r] = v.y; ht[kq + 2][r] = v.z; ht[kq + 3][r] = v.w;
  }
  float M = -INFINITY, S = 0.f, Tl = 0.f;
  int Iv = 0, tgtv = -1;
  if (tid < 64) {
    int r = r0 + tid, t = r >> 5, b = r & 31;
    tgtv = tgt_word[b * Lq + t];
  }
  int nvt = min(8, (VOC - v0 + 63) >> 6);
  int tx = tid & 15, ty = tid >> 4;
  for (int vt = 0; vt < nvt; ++vt) {
    int vbase = v0 + vt * 64;
    __syncthreads();
#pragma unroll
    for (int j = 0; j < 8; ++j) {
      int f = tid + 256 * j;
      int v = f >> 5, kq = (f & 31) * 4;
      int vg = vbase + v;
      float4 x = make_float4(0.f, 0.f, 0.f, 0.f);
      if (vg < VOC) x = *(const float4*)&w2[(size_t)vg * 128 + kq];
      wt[kq + 0][v] = x.x; wt[kq + 1][v] = x.y; wt[kq + 2][v] = x.z; wt[kq + 3][v] = x.w;
    }
    __syncthreads();
    float acc[4][4];
#pragma unroll
    for (int i = 0; i < 4; ++i)
#pragma unroll
      for (int j = 0; j < 4; ++j) acc[i][j] = 0.f;
#pragma unroll 4
    for (int k = 0; k < 128; ++k) {
      float a[4], w[4];
      *(float4*)a = *(const float4*)&ht[k][ty * 4];
      *(float4*)w = *(const float4*)&wt[k][tx * 4];
#pragma unroll
      for (int i = 0; i < 4; ++i)
#pragma unroll
        for (int j = 0; j < 4; ++j)
          acc[i][j] = fmaf(a[i], w[j], acc[i][j]);
    }
#pragma unroll
    for (int i = 0; i < 4; ++i)
#pragma unroll
      for (int j = 0; j < 4; ++j) {
        int v = vbase + tx * 4 + j;
        lg[ty * 4 + i][tx * 4 + j] = acc[i][j] + (v < VOC ? b2[v] : 0.f);
      }
    __syncthreads();
    if (tid < 64) {
      for (int j = 0; j < 64; ++j) {
        int v = vbase + j;
        if (v >= VOC) break;
        float val = lg[tid][j];
        if (val > M) { S = S * expf(M - val) + 1.f; M = val; Iv = v; }
        else S += expf(val - M);
        if (v == tgtv) Tl = val;
      }
    }
  }
  if (tid < 64) {
    int r = r0 + tid;
    float4 o; o.x = M; o.y = S; o.z = (float)Iv; o.w = Tl;
    *(float4*)&part[((size_t)vb * 4096 + r) * 4] = o;
  }
}

// ---------------- combine chunks per row; write argmax + per-row weighted nll ----------------
__global__ __launch_bounds__(256) void dec_fin_k(
    const float* __restrict__ part, const int* __restrict__ tgt_word,
    const float* __restrict__ cew, float* __restrict__ out,
    float* __restrict__ rowred) {
  int r = blockIdx.x * 256 + threadIdx.x;   // 0..4095
  float M = -INFINITY, S = 0.f, If = 0.f;
  for (int ch = 0; ch < 63; ++ch) {
    float4 p = *(const float4*)&part[((size_t)ch * 4096 + r) * 4];
    if (p.x > M) { S = S * expf(M - p.x) + p.y; M = p.x; If = p.z; }
    else S += p.y * expf(p.x - M);
  }
  int t = r >> 5, b = r & 31;
  int tgt = tgt_word[b * Lq + t];
  float Tl = part[((size_t)(tgt >> 9) * 4096 + r) * 4 + 3];
  float lse = M + logf(S);
  float w = cew[tgt];
  out[1 + b * Lq + t] = If;
  rowred[r] = (lse - Tl) * w;
  rowred[4096 + r] = w;
}

__global__ __launch_bounds__(256) void loss_k(const float* __restrict__ rowred,
                                              float* __restrict__ out) {
  __shared__ float s1[256], s2[256];
  float a = 0.f, c = 0.f;
  for (int r = threadIdx.x; r < 4096; r += 256) { a += rowred[r]; c += rowred[4096 + r]; }
  s1[threadIdx.x] = a; s2[threadIdx.x] = c;
  __syncthreads();
  for (int o = 128; o > 0; o >>= 1) {
    if ((int)threadIdx.x < o) { s1[threadIdx.x] += s1[threadIdx.x + o]; s2[threadIdx.x] += s2[threadIdx.x + o]; }
    __syncthreads();
  }
  if (threadIdx.x == 0) out[0] = s1[0] / s2[0];
}

extern "C" void kernel_launch(void* const* d_in, const int* in_sizes, int n_in,
                              void* d_out, int out_size, void* d_ws, size_t ws_size,
                              hipStream_t stream) {
  (void)in_sizes; (void)n_in; (void)out_size; (void)ws_size;
  const int*   inp_word = (const int*)d_in[0];
  const float* inp_mask = (const float*)d_in[1];
  const int*   tgt_word = (const int*)d_in[3];
  const float* emb      = (const float*)d_in[4];
  const float* w_ih0    = (const float*)d_in[5];
  const float* w_hh0    = (const float*)d_in[6];
  const float* b0       = (const float*)d_in[7];
  const float* w_ih     = (const float*)d_in[8];
  const float* w_hh     = (const float*)d_in[9];
  const float* bb       = (const float*)d_in[10];
  const float* dec_w1   = (const float*)d_in[11];
  const float* dec_b1   = (const float*)d_in[12];
  const float* dec_w2   = (const float*)d_in[13];
  const float* dec_b2   = (const float*)d_in[14];
  const float* cew      = (const float*)d_in[15];
  float* out = (float*)d_out;
  float* ws  = (float*)d_ws;

  float* x_tm   = ws;                      // 524288
  float* seqA   = x_tm + 524288;           // 4194304
  float* seqB   = seqA + 4194304;          // 4194304
  float* GX     = seqB + 4194304;          // 16777216
  float* hid    = GX + 16777216;           // 524288
  float* Hst    = hid + 524288;            // 2 parity * 2 dir * 16384 = 65536
  float* Cst    = Hst + 65536;             // 32768
  float* part   = Cst + 32768;             // 63*4096*4 = 1032192
  float* rowred = part + 1032192;          // 8192

  embed_k<<<2048, 256, 0, stream>>>(inp_word, emb, x_tm);

  // ---- layer 0 ----
  gemm_k<<<dim3(32, 32), 256, 0, stream>>>(x_tm, w_ih0, b0, GX, 4096, 128, 0);
  hipMemsetAsync(Hst, 0, (65536 + 32768) * sizeof(float), stream);
  for (int s = 0; s < 128; ++s)
    lstm_step_k<<<256, 256, 0, stream>>>(GX, w_hh0, inp_mask,
        Hst + (s & 1) * 32768, Hst + ((s & 1) ^ 1) * 32768, Cst, seqA, s);

  // ---- layer 1 ----
  gemm_k<<<dim3(32, 32), 256, 0, stream>>>(seqA, w_ih, bb, GX, 4096, 1024, 0);
  hipMemsetAsync(Hst, 0, (65536 + 32768) * sizeof(float), stream);
  for (int s = 0; s < 128; ++s)
    lstm_step_k<<<256, 256, 0, stream>>>(GX, w_hh, inp_mask,
        Hst + (s & 1) * 32768, Hst + ((s & 1) ^ 1) * 32768, Cst, seqB, s);

  // ---- layer 2 ----
  gemm_k<<<dim3(32, 32), 256, 0, stream>>>(seqB, w_ih + (size_t)2 * 2048 * 1024,
                                           bb + 4096, GX, 4096, 1024, 0);
  hipMemsetAsync(Hst, 0, (65536 + 32768) * sizeof(float), stream);
  for (int s = 0; s < 128; ++s)
    lstm_step_k<<<256, 256, 0, stream>>>(GX, w_hh + (size_t)2 * 2048 * 512, inp_mask,
        Hst + (s & 1) * 32768, Hst + ((s & 1) ^ 1) * 32768, Cst, seqA, s);

  // ---- decoder ----
  gemm_k<<<dim3(1, 32), 256, 0, stream>>>(seqA, dec_w1, dec_b1, hid, 128, 1024, 1);
  dec_k<<<dim3(63, 64), 256, 0, stream>>>(hid, dec_w2, dec_b2, tgt_word, part);
  dec_fin_k<<<16, 256, 0, stream>>>(part, tgt_word, cew, out, rowred);
  loss_k<<<1, 256, 0, stream>>>(rowred, out);
}